// Round 10
// baseline (445.241 us; speedup 1.0000x reference)
//
#include <hip/hip_runtime.h>

typedef unsigned int       u32;
typedef unsigned long long u64;

#define NB 4
#define NQ 8192
#define WS_NEEDED (512u*1024 + 256u*1024 + 128u*1024 + 512u*1024)

struct DM { double x, y, z, w; };   // mask candidate: x,y,z,|k|^2 (f64)

// lexicographic (d, idx) insert into sorted triple; ties -> lower index
// (matches jax.lax.top_k stability)
__device__ __forceinline__ void lexins(double& e0d, double& e1d, double& e2d,
                                       int& e0i, int& e1i, int& e2i,
                                       double d, int i) {
  if (d < e2d || (d == e2d && i < e2i)) {
    if (d < e0d || (d == e0d && i < e0i)) {
      e2d = e1d; e2i = e1i; e1d = e0d; e1i = e0i; e0d = d; e0i = i;
    } else if (d < e1d || (d == e1d && i < e1i)) {
      e2d = e1d; e2i = e1i; e1d = d; e1i = i;
    } else {
      e2d = d; e2i = i;
    }
  }
}

struct Smem {
  float  qx[64], qy[64], qz[64];            // f32 queries (prefilter)
  double qdx[64], qdy[64], qdz[64], qn[64]; // f64 queries (rescore)
  float  dk[3][64][4][4];                   // per-level/query/part top-4 keys
  u32    di[3][64][4][4];                   // matching indices
  double mmin[64][8];                       // per-wave mask min s
  float  wv[96];                            // folded w_cls @ w_fc
  float  part[64][3];                       // per-level partial pred
};

// ---------------- prep: materialize |k|^2 so scans don't recompute it -------
__global__ __launch_bounds__(256) void prep_kernel(
    const float* __restrict__ k2p, const float* __restrict__ k3p,
    const float* __restrict__ k4p, const float* __restrict__ mmp,
    float4* __restrict__ c0, float4* __restrict__ c1,
    float4* __restrict__ c2, DM* __restrict__ cm) {
  int r = blockIdx.y;
  int i = blockIdx.x * 256 + threadIdx.x;
  if (r < 3) {
    const float* src = (r == 0) ? k2p : ((r == 1) ? k3p : k4p);
    float4* dst = (r == 0) ? c0 : ((r == 1) ? c1 : c2);
    int count = (r == 0) ? NB * 8192 : ((r == 1) ? NB * 4096 : NB * 2048);
    if (i >= count) return;
    float x = src[3 * i], y = src[3 * i + 1], z = src[3 * i + 2];
    // UNBIASED |k|^2: key magnitudes ~1e2..1e3, f32 key error ~1e-4
    float n2 = fmaf(z, z, fmaf(y, y, x * x));
    dst[i] = make_float4(x, y, z, n2);
  } else {
    if (i >= NB * 4096) return;
    double x = (double)mmp[3 * i], y = (double)mmp[3 * i + 1], z = (double)mmp[3 * i + 2];
    DM d = {x, y, z, fma(z, z, fma(y, y, x * x))};   // products exact in f64
    cm[i] = d;
  }
}

// f32 prefilter scan over [gstart, gstart+L) of one candidate array.
// Wave-uniform addresses -> scalar (SGPR) loads, software-pipelined one
// 16-candidate group ahead so the ~250-cyc L2 scalar-load latency hides
// under the previous group's FMAs + guarded inserts.
// key = |k|^2 - 2 p.k (unbiased); per-part top-4 union is f64-rescored, so a
// true-top-3 loss needs TWO consecutive d2 gaps < ~1e-4 (negligible).
template <bool PREP>
__device__ __forceinline__ void scan_nn(
    const float4* __restrict__ c4, const float* __restrict__ raw,
    int gstart, int L, float m2x, float m2y, float m2z,
    float* kk, u32* ii) {
  float k0 = __builtin_inff(), k1 = k0, k2 = k0, k3 = k0;
  u32 i0 = 0, i1 = 0, i2 = 0, i3 = 0;

  if (PREP) {
    float4 buf[16];                       // wave-uniform -> lives in SGPRs
#pragma unroll
    for (int u = 0; u < 16; ++u) buf[u] = c4[gstart + u];
    for (int j = 0; j < L; j += 16) {
      float key[16];
#pragma unroll
      for (int u = 0; u < 16; ++u) {      // waits on loads issued last iter
        float4 c = buf[u];
        key[u] = fmaf(m2x, c.x, fmaf(m2y, c.y, fmaf(m2z, c.z, c.w)));
      }
      // prefetch the NEXT group before the inserts (in-order issue makes the
      // overwrite safe; clamped index keeps the last iteration branchless)
      int jn = (j + 16 < L) ? (j + 16) : j;
#pragma unroll
      for (int u = 0; u < 16; ++u) buf[u] = c4[gstart + jn + u];
#pragma unroll
      for (int u = 0; u < 16; ++u) {
        float kv = key[u];
        if (kv < k3) {             // strict: tie keeps incumbent (lower idx)
          u32 idx = (u32)(gstart + j + u);
          bool lt0 = kv < k0, lt1 = kv < k1, lt2 = kv < k2;
          k3 = lt2 ? k2 : kv;               i3 = lt2 ? i2 : idx;
          k2 = lt2 ? (lt1 ? k1 : kv) : k2;  i2 = lt2 ? (lt1 ? i1 : idx) : i2;
          k1 = lt1 ? (lt0 ? k0 : kv) : k1;  i1 = lt1 ? (lt0 ? i0 : idx) : i1;
          k0 = lt0 ? kv : k0;               i0 = lt0 ? idx : i0;
        }
      }
    }
  } else {
    for (int j = 0; j < L; j += 8) {
      float key[8];
#pragma unroll
      for (int u = 0; u < 8; ++u) {
        const float* p = raw + (size_t)(gstart + j + u) * 3;
        float x = p[0], y = p[1], z = p[2];
        float n2 = fmaf(z, z, fmaf(y, y, x * x));
        key[u] = fmaf(m2x, x, fmaf(m2y, y, fmaf(m2z, z, n2)));
      }
#pragma unroll
      for (int u = 0; u < 8; ++u) {
        float kv = key[u];
        if (kv < k3) {
          u32 idx = (u32)(gstart + j + u);
          bool lt0 = kv < k0, lt1 = kv < k1, lt2 = kv < k2;
          k3 = lt2 ? k2 : kv;               i3 = lt2 ? i2 : idx;
          k2 = lt2 ? (lt1 ? k1 : kv) : k2;  i2 = lt2 ? (lt1 ? i1 : idx) : i2;
          k1 = lt1 ? (lt0 ? k0 : kv) : k1;  i1 = lt1 ? (lt0 ? i0 : idx) : i1;
          k0 = lt0 ? kv : k0;               i0 = lt0 ? idx : i0;
        }
      }
    }
  }
  kk[0] = k0; kk[1] = k1; kk[2] = k2; kk[3] = k3;
  ii[0] = i0; ii[1] = i1; ii[2] = i2; ii[3] = i3;
}

// f64 mask scan (0.25 threshold is discontinuous -> full f64, precomputed kn),
// software-pipelined one 8-candidate group ahead, min-tree reduction.
template <bool PREP>
__device__ __forceinline__ double scan_mask(
    const DM* __restrict__ c8, const float* __restrict__ raw,
    int gstart, int L, double m2x, double m2y, double m2z) {
  double smin = __builtin_inf();
  if (PREP) {
    DM buf[8];                            // wave-uniform -> SGPRs
#pragma unroll
    for (int u = 0; u < 8; ++u) buf[u] = c8[gstart + u];
    for (int j = 0; j < L; j += 8) {
      double sv[8];
#pragma unroll
      for (int u = 0; u < 8; ++u) {
        DM c = buf[u];
        sv[u] = fma(m2x, c.x, fma(m2y, c.y, fma(m2z, c.z, c.w)));
      }
      int jn = (j + 8 < L) ? (j + 8) : j;
#pragma unroll
      for (int u = 0; u < 8; ++u) buf[u] = c8[gstart + jn + u];
      // min-tree (min is associative; no NaNs here) -> 3-deep not 8-deep
      double m01 = fmin(sv[0], sv[1]), m23 = fmin(sv[2], sv[3]);
      double m45 = fmin(sv[4], sv[5]), m67 = fmin(sv[6], sv[7]);
      smin = fmin(smin, fmin(fmin(m01, m23), fmin(m45, m67)));
    }
  } else {
    for (int j = 0; j < L; j += 4) {
#pragma unroll
      for (int u = 0; u < 4; ++u) {
        const float* p = raw + (size_t)(gstart + j + u) * 3;
        double x = (double)p[0], y = (double)p[1], z = (double)p[2];
        double kn = fma(z, z, fma(y, y, x * x));
        smin = fmin(smin, fma(m2x, x, fma(m2y, y, fma(m2z, z, kn))));
      }
    }
  }
  return smin;
}

template <bool PREP>
__global__ __launch_bounds__(512, 2) void fused_kernel(
    const float* __restrict__ pts,
    const float* __restrict__ k2p, const float* __restrict__ f2,
    const float* __restrict__ k3p, const float* __restrict__ f3,
    const float* __restrict__ k4p, const float* __restrict__ f4,
    const float* __restrict__ mmp,
    const float* __restrict__ wfc, const float* __restrict__ wcls,
    const float4* __restrict__ c0, const float4* __restrict__ c1,
    const float4* __restrict__ c2, const DM* __restrict__ cm,
    float* __restrict__ out) {
  __shared__ Smem s;
  const int tid = threadIdx.x;
  const int b = blockIdx.y;
  const int q0 = blockIdx.x * 64;
  const int qloc = tid & 63;
  const int wid = __builtin_amdgcn_readfirstlane(tid >> 6);  // wave 0..7

  // phase 1: wave 0 loads queries; threads 64..159 fold w_cls @ w_fc
  if (tid < 64) {
    int gq = b * NQ + q0 + tid;
    float x = pts[3 * gq], y = pts[3 * gq + 1], z = pts[3 * gq + 2];
    s.qx[tid] = x; s.qy[tid] = y; s.qz[tid] = z;
    double dx = (double)x, dy = (double)y, dz = (double)z;
    s.qdx[tid] = dx; s.qdy[tid] = dy; s.qdz[tid] = dz;
    s.qn[tid] = (dx * dx + dy * dy) + dz * dz;   // numpy f64 grouping
  } else if (tid < 160) {
    int t = tid - 64;
    float acc = 0.f;
    for (int j = 0; j < 64; ++j) acc += wcls[j] * wfc[j * 96 + t];
    s.wv[t] = acc;
  }
  __syncthreads();

  const float fm2x = -2.0f * s.qx[qloc];
  const float fm2y = -2.0f * s.qy[qloc];
  const float fm2z = -2.0f * s.qz[qloc];
  const double dm2x = -2.0 * s.qdx[qloc];
  const double dm2y = -2.0 * s.qdy[qloc];
  const double dm2z = -2.0 * s.qdz[qloc];

  // phase 2: load-balanced static partition (~equal wave-instr budgets):
  //   w0-3: c0 quarters (2048) | w4,5: c1 halves (2048) | w6,7: c2 halves (1024)
  //   mask: w0-5 get 256 each, w6,7 get 1280 each.
  {
    int lvl, prt, gstart, glen;
    if (wid < 4)      { lvl = 0; prt = wid;     gstart = wid * 2048;       glen = 2048; }
    else if (wid < 6) { lvl = 1; prt = wid - 4; gstart = (wid - 4) * 2048; glen = 2048; }
    else              { lvl = 2; prt = wid - 6; gstart = (wid - 6) * 1024; glen = 1024; }
    const float4* c4 = (lvl == 0) ? c0 : ((lvl == 1) ? c1 : c2);
    const float* raw = (lvl == 0) ? k2p : ((lvl == 1) ? k3p : k4p);
    const int      M = (lvl == 0) ? 8192 : ((lvl == 1) ? 4096 : 2048);
    float kk[4]; u32 ii[4];
    scan_nn<PREP>(c4 + (PREP ? (size_t)b * M : 0), raw + (size_t)b * M * 3,
                  gstart, glen, fm2x, fm2y, fm2z, kk, ii);
#pragma unroll
    for (int r = 0; r < 4; ++r) {
      s.dk[lvl][qloc][prt][r] = kk[r];
      s.di[lvl][qloc][prt][r] = ii[r];
    }

    int mstart, mlen;
    if (wid < 6) { mstart = wid * 256; mlen = 256; }
    else         { mstart = 1536 + (wid - 6) * 1280; mlen = 1280; }
    s.mmin[qloc][wid] = scan_mask<PREP>(cm + (PREP ? (size_t)b * 4096 : 0),
                                        mmp + (size_t)b * 4096 * 3,
                                        mstart, mlen, dm2x, dm2y, dm2z);
  }
  __syncthreads();

  // phase 3: f64 rescore of the full per-level union (ref-exact grouping),
  // weights, feature gather, folded FC; thread range 192..255 does the mask.
  const int gqbase = b * NQ + q0;
  if (tid < 192) {
    const int lvl = __builtin_amdgcn_readfirstlane(tid >> 6);
    const int q = tid & 63;
    const float* kp = (lvl == 0) ? k2p : ((lvl == 1) ? k3p : k4p);
    const int    M  = (lvl == 0) ? 8192 : ((lvl == 1) ? 4096 : 2048);
    const int    np = (lvl == 0) ? 4 : 2;
    const double qdx = s.qdx[q], qdy = s.qdy[q], qdz = s.qdz[q], qn = s.qn[q];
    double e0 = __builtin_inf(), e1 = e0, e2 = e0;
    int i0 = 0, i1 = 0, i2 = 0;
    for (int h = 0; h < np; ++h) {
#pragma unroll
      for (int r = 0; r < 4; ++r) {
        int idx = (int)s.di[lvl][q][h][r];
        const float* c = kp + ((size_t)b * M + idx) * 3;
        double x = (double)c[0], y = (double)c[1], z = (double)c[2];
        double kn2 = (x * x + y * y) + z * z;         // ref grouping
        double dot = (qdx * x + qdy * y) + qdz * z;   // products exact
        double d2 = (qn + kn2) - 2.0 * dot;
        lexins(e0, e1, e2, i0, i1, i2, d2, idx);
      }
    }
    double d0 = fmax(e0, 0.0), d1 = fmax(e1, 0.0), d2v = fmax(e2, 0.0);
    double r0 = 1.0 / (d0 + 1e-8);
    double r1 = 1.0 / (d1 + 1e-8);
    double r2 = 1.0 / (d2v + 1e-8);
    double sum = (r0 + r1) + r2;
    float wa = (float)(r0 / sum), wb = (float)(r1 / sum), wc = (float)(r2 / sum);

    const float* fp = (lvl == 0) ? f2 : ((lvl == 1) ? f3 : f4);
    const float* g0 = fp + ((size_t)b * M + i0) * 32;
    const float* g1 = fp + ((size_t)b * M + i1) * 32;
    const float* g2 = fp + ((size_t)b * M + i2) * 32;
    float acc = 0.f;
#pragma unroll
    for (int wd = 0; wd < 32; ++wd) {
      float v = (wa * g0[wd] + wb * g1[wd]) + wc * g2[wd];
      acc += s.wv[lvl * 32 + wd] * v;
    }
    s.part[q][lvl] = acc;
  } else if (tid < 256) {
    const int q = tid - 192;
    double sm = s.mmin[q][0];
#pragma unroll
    for (int p = 1; p < 8; ++p) sm = fmin(sm, s.mmin[q][p]);
    double dm = s.qn[q] + sm;   // monotone rounding: == min of per-cand d2
    // d2 < 0.25 == sqrt(max(d2,0)) < 0.5 (monotone, both strict)
    out[NB * NQ + gqbase + q] = (dm < 0.25) ? 1.0f : 0.0f;
  }
  __syncthreads();
  if (tid < 64) {
    float pred = (s.part[tid][0] + s.part[tid][1]) + s.part[tid][2];
    out[gqbase + tid] = pred;
  }
}

extern "C" void kernel_launch(void* const* d_in, const int* in_sizes, int n_in,
                              void* d_out, int out_size, void* d_ws, size_t ws_size,
                              hipStream_t stream) {
  const float* pts    = (const float*)d_in[0];
  const float* known2 = (const float*)d_in[1];
  const float* feats2 = (const float*)d_in[2];
  const float* known3 = (const float*)d_in[3];
  const float* feats3 = (const float*)d_in[4];
  const float* known4 = (const float*)d_in[5];
  const float* feats4 = (const float*)d_in[6];
  const float* match  = (const float*)d_in[7];
  const float* wfc    = (const float*)d_in[8];
  const float* wcls   = (const float*)d_in[9];

  char* ws = (char*)d_ws;
  float4* c0 = (float4*)(ws);
  float4* c1 = (float4*)(ws + (size_t)512 * 1024);
  float4* c2 = (float4*)(ws + (size_t)768 * 1024);
  DM*     cm = (DM*)   (ws + (size_t)896 * 1024);

  if (ws_size >= WS_NEEDED) {
    hipLaunchKernelGGL(prep_kernel, dim3(128, 4), dim3(256), 0, stream,
                       known2, known3, known4, match, c0, c1, c2, cm);
    hipLaunchKernelGGL(fused_kernel<true>, dim3(NQ / 64, NB), dim3(512), 0,
                       stream, pts, known2, feats2, known3, feats3, known4,
                       feats4, match, wfc, wcls, c0, c1, c2, cm, (float*)d_out);
  } else {
    hipLaunchKernelGGL(fused_kernel<false>, dim3(NQ / 64, NB), dim3(512), 0,
                       stream, pts, known2, feats2, known3, feats3, known4,
                       feats4, match, wfc, wcls, c0, c1, c2, cm, (float*)d_out);
  }
}

// Round 11
// 323.087 us; speedup vs baseline: 1.3781x; 1.3781x over previous
//
#include <hip/hip_runtime.h>

typedef unsigned int u32;
typedef float f32x2 __attribute__((ext_vector_type(2)));

#define NB 4
#define NQ 8192
#define WS_NEEDED (512u*1024 + 256u*1024 + 128u*1024 + 512u*1024)

struct __align__(32) CP { f32x2 x, y, z, w; };  // 2 candidates, SoA-paired
struct DM { double x, y, z, w; };               // mask cand: x,y,z,|k|^2 (f64)

__device__ __forceinline__ f32x2 fma2(f32x2 a, f32x2 b, f32x2 c) {
  return __builtin_elementwise_fma(a, b, c);    // v_pk_fma_f32 on gfx950
}

// lexicographic (d, idx) insert into sorted triple; ties -> lower index
// (matches jax.lax.top_k stability)
__device__ __forceinline__ void lexins(double& e0d, double& e1d, double& e2d,
                                       int& e0i, int& e1i, int& e2i,
                                       double d, int i) {
  if (d < e2d || (d == e2d && i < e2i)) {
    if (d < e0d || (d == e0d && i < e0i)) {
      e2d = e1d; e2i = e1i; e1d = e0d; e1i = e0i; e0d = d; e0i = i;
    } else if (d < e1d || (d == e1d && i < e1i)) {
      e2d = e1d; e2i = e1i; e1d = d; e1i = i;
    } else {
      e2d = d; e2i = i;
    }
  }
}

// guarded 4-deep unpacked insert; strict < keeps incumbent (lower idx)
__device__ __forceinline__ void ins4(float kv, u32 idx,
                                     float& k0, float& k1, float& k2, float& k3,
                                     u32& i0, u32& i1, u32& i2, u32& i3) {
  if (kv < k3) {
    bool lt0 = kv < k0, lt1 = kv < k1, lt2 = kv < k2;
    k3 = lt2 ? k2 : kv;               i3 = lt2 ? i2 : idx;
    k2 = lt2 ? (lt1 ? k1 : kv) : k2;  i2 = lt2 ? (lt1 ? i1 : idx) : i2;
    k1 = lt1 ? (lt0 ? k0 : kv) : k1;  i1 = lt1 ? (lt0 ? i0 : idx) : i1;
    k0 = lt0 ? kv : k0;               i0 = lt0 ? idx : i0;
  }
}

struct Smem {
  float  qx[64], qy[64], qz[64];            // f32 queries (prefilter)
  double qdx[64], qdy[64], qdz[64], qn[64]; // f64 queries (rescore)
  float  dk[3][64][4][4];                   // per-level/query/part top-4 keys
  u32    di[3][64][4][4];                   // matching indices
  double mmin[64][8];                       // per-wave mask min s
  float  wv[96];                            // folded w_cls @ w_fc
  float  part[64][3];                       // per-level partial pred
};

// ---------------- prep: SoA-paired candidates + precomputed |k|^2 ----------
__global__ __launch_bounds__(256) void prep_kernel(
    const float* __restrict__ k2p, const float* __restrict__ k3p,
    const float* __restrict__ k4p, const float* __restrict__ mmp,
    CP* __restrict__ c0, CP* __restrict__ c1,
    CP* __restrict__ c2, DM* __restrict__ cm) {
  int r = blockIdx.y;
  int i = blockIdx.x * 256 + threadIdx.x;
  if (r < 3) {
    const float* src = (r == 0) ? k2p : ((r == 1) ? k3p : k4p);
    CP* dst = (r == 0) ? c0 : ((r == 1) ? c1 : c2);
    int pairs = (r == 0) ? NB * 4096 : ((r == 1) ? NB * 2048 : NB * 1024);
    if (i >= pairs) return;
    const float* p = src + (size_t)i * 6;
    float x0 = p[0], y0 = p[1], z0 = p[2];
    float x1 = p[3], y1 = p[4], z1 = p[5];
    CP c;
    c.x = f32x2{x0, x1}; c.y = f32x2{y0, y1}; c.z = f32x2{z0, z1};
    // UNBIASED |k|^2: key magnitudes ~1e2..1e3, f32 key error ~1e-4
    c.w = f32x2{fmaf(z0, z0, fmaf(y0, y0, x0 * x0)),
                fmaf(z1, z1, fmaf(y1, y1, x1 * x1))};
    dst[i] = c;
  } else {
    if (i >= NB * 4096) return;
    double x = (double)mmp[3 * i], y = (double)mmp[3 * i + 1], z = (double)mmp[3 * i + 2];
    DM d = {x, y, z, fma(z, z, fma(y, y, x * x))};   // products exact in f64
    cm[i] = d;
  }
}

// f32 prefilter scan, packed-pair form. Wave-uniform addresses -> scalar
// loads; per candidate PAIR: 3 v_pk_fma_f32 + 1 fmin + 1 cmp, plus the
// ~19-op insert ladder on rare hit iterations (per-candidate, in index
// order -> selection semantics identical to the scalar scan).
// key = |k|^2 - 2 p.k; per-part top-4 union is f64-rescored, so a true-top-3
// loss needs TWO consecutive d2 gaps < ~1e-4 (negligible).
template <bool PREP>
__device__ __forceinline__ void scan_nn(
    const CP* __restrict__ cp, const float* __restrict__ raw,
    int gstart, int L, float m2x, float m2y, float m2z,
    float* kk, u32* ii) {
  float k0 = __builtin_inff(), k1 = k0, k2 = k0, k3 = k0;
  u32 i0 = 0, i1 = 0, i2 = 0, i3 = 0;

  if (PREP) {
    const f32x2 mx2 = {m2x, m2x}, my2 = {m2y, m2y}, mz2 = {m2z, m2z};
    const int G = L >> 1;            // pairs
#pragma unroll 2
    for (int g = 0; g < G; g += 4) { // 8 candidates per group
      f32x2 key[4];
#pragma unroll
      for (int u = 0; u < 4; ++u) {
        CP c = cp[g + u];            // uniform -> s_load, 32B
        key[u] = fma2(mx2, c.x, fma2(my2, c.y, fma2(mz2, c.z, c.w)));
      }
#pragma unroll
      for (int u = 0; u < 4; ++u) {
        float ka = key[u].x, kb = key[u].y;
        if (fminf(ka, kb) < k3) {
          u32 ib = (u32)(gstart + 2 * (g + u));
          ins4(ka, ib,     k0, k1, k2, k3, i0, i1, i2, i3);
          ins4(kb, ib + 1, k0, k1, k2, k3, i0, i1, i2, i3);
        }
      }
    }
  } else {
    for (int j = 0; j < L; j += 8) {
      float key[8];
#pragma unroll
      for (int u = 0; u < 8; ++u) {
        const float* p = raw + (size_t)(gstart + j + u) * 3;
        float x = p[0], y = p[1], z = p[2];
        float n2 = fmaf(z, z, fmaf(y, y, x * x));
        key[u] = fmaf(m2x, x, fmaf(m2y, y, fmaf(m2z, z, n2)));
      }
#pragma unroll
      for (int u = 0; u < 8; ++u)
        ins4(key[u], (u32)(gstart + j + u), k0, k1, k2, k3, i0, i1, i2, i3);
    }
  }
  kk[0] = k0; kk[1] = k1; kk[2] = k2; kk[3] = k3;
  ii[0] = i0; ii[1] = i1; ii[2] = i2; ii[3] = i3;
}

// f64 mask scan (0.25 threshold is discontinuous -> full f64), 8-wide with a
// min-tree (min is associative, no NaNs -> any order gives the same min).
template <bool PREP>
__device__ __forceinline__ double scan_mask(
    const DM* __restrict__ c8, const float* __restrict__ raw,
    int gstart, int L, double m2x, double m2y, double m2z) {
  double smin = __builtin_inf();
  if (PREP) {
    for (int j = 0; j < L; j += 8) {
      double sv[8];
#pragma unroll
      for (int u = 0; u < 8; ++u) {
        DM c = c8[gstart + j + u];
        sv[u] = fma(m2x, c.x, fma(m2y, c.y, fma(m2z, c.z, c.w)));
      }
      double m01 = fmin(sv[0], sv[1]), m23 = fmin(sv[2], sv[3]);
      double m45 = fmin(sv[4], sv[5]), m67 = fmin(sv[6], sv[7]);
      smin = fmin(smin, fmin(fmin(m01, m23), fmin(m45, m67)));
    }
  } else {
    for (int j = 0; j < L; j += 4) {
#pragma unroll
      for (int u = 0; u < 4; ++u) {
        const float* p = raw + (size_t)(gstart + j + u) * 3;
        double x = (double)p[0], y = (double)p[1], z = (double)p[2];
        double kn = fma(z, z, fma(y, y, x * x));
        smin = fmin(smin, fma(m2x, x, fma(m2y, y, fma(m2z, z, kn))));
      }
    }
  }
  return smin;
}

template <bool PREP>
__global__ __launch_bounds__(512, 2) void fused_kernel(
    const float* __restrict__ pts,
    const float* __restrict__ k2p, const float* __restrict__ f2,
    const float* __restrict__ k3p, const float* __restrict__ f3,
    const float* __restrict__ k4p, const float* __restrict__ f4,
    const float* __restrict__ mmp,
    const float* __restrict__ wfc, const float* __restrict__ wcls,
    const CP* __restrict__ c0, const CP* __restrict__ c1,
    const CP* __restrict__ c2, const DM* __restrict__ cm,
    float* __restrict__ out) {
  __shared__ Smem s;
  const int tid = threadIdx.x;
  const int b = blockIdx.y;
  const int q0 = blockIdx.x * 64;
  const int qloc = tid & 63;
  const int wid = __builtin_amdgcn_readfirstlane(tid >> 6);  // wave 0..7

  // phase 1: wave 0 loads queries; threads 64..159 fold w_cls @ w_fc
  if (tid < 64) {
    int gq = b * NQ + q0 + tid;
    float x = pts[3 * gq], y = pts[3 * gq + 1], z = pts[3 * gq + 2];
    s.qx[tid] = x; s.qy[tid] = y; s.qz[tid] = z;
    double dx = (double)x, dy = (double)y, dz = (double)z;
    s.qdx[tid] = dx; s.qdy[tid] = dy; s.qdz[tid] = dz;
    s.qn[tid] = (dx * dx + dy * dy) + dz * dz;   // numpy f64 grouping
  } else if (tid < 160) {
    int t = tid - 64;
    float acc = 0.f;
    for (int j = 0; j < 64; ++j) acc += wcls[j] * wfc[j * 96 + t];
    s.wv[t] = acc;
  }
  __syncthreads();

  const float fm2x = -2.0f * s.qx[qloc];
  const float fm2y = -2.0f * s.qy[qloc];
  const float fm2z = -2.0f * s.qz[qloc];
  const double dm2x = -2.0 * s.qdx[qloc];
  const double dm2y = -2.0 * s.qdy[qloc];
  const double dm2z = -2.0 * s.qdz[qloc];

  // phase 2: load-balanced static partition (~equal wave-instr budgets):
  //   w0-3: c0 quarters (2048) | w4,5: c1 halves (2048) | w6,7: c2 halves (1024)
  //   mask: w0-5 get 256 each, w6,7 get 1280 each.
  {
    int lvl, prt, gstart, glen;
    if (wid < 4)      { lvl = 0; prt = wid;     gstart = wid * 2048;       glen = 2048; }
    else if (wid < 6) { lvl = 1; prt = wid - 4; gstart = (wid - 4) * 2048; glen = 2048; }
    else              { lvl = 2; prt = wid - 6; gstart = (wid - 6) * 1024; glen = 1024; }
    const CP* c4 = (lvl == 0) ? c0 : ((lvl == 1) ? c1 : c2);
    const float* raw = (lvl == 0) ? k2p : ((lvl == 1) ? k3p : k4p);
    const int      M = (lvl == 0) ? 8192 : ((lvl == 1) ? 4096 : 2048);
    float kk[4]; u32 ii[4];
    scan_nn<PREP>(c4 + (PREP ? (((size_t)b * M + gstart) >> 1) : 0),
                  raw + (size_t)b * M * 3,
                  gstart, glen, fm2x, fm2y, fm2z, kk, ii);
#pragma unroll
    for (int r = 0; r < 4; ++r) {
      s.dk[lvl][qloc][prt][r] = kk[r];
      s.di[lvl][qloc][prt][r] = ii[r];
    }

    int mstart, mlen;
    if (wid < 6) { mstart = wid * 256; mlen = 256; }
    else         { mstart = 1536 + (wid - 6) * 1280; mlen = 1280; }
    s.mmin[qloc][wid] = scan_mask<PREP>(cm + (PREP ? (size_t)b * 4096 : 0),
                                        mmp + (size_t)b * 4096 * 3,
                                        mstart, mlen, dm2x, dm2y, dm2z);
  }
  __syncthreads();

  // phase 3: f64 rescore of the full per-level union (ref-exact grouping),
  // weights, feature gather, folded FC; thread range 192..255 does the mask.
  const int gqbase = b * NQ + q0;
  if (tid < 192) {
    const int lvl = __builtin_amdgcn_readfirstlane(tid >> 6);
    const int q = tid & 63;
    const float* kp = (lvl == 0) ? k2p : ((lvl == 1) ? k3p : k4p);
    const int    M  = (lvl == 0) ? 8192 : ((lvl == 1) ? 4096 : 2048);
    const int    np = (lvl == 0) ? 4 : 2;
    const double qdx = s.qdx[q], qdy = s.qdy[q], qdz = s.qdz[q], qn = s.qn[q];
    double e0 = __builtin_inf(), e1 = e0, e2 = e0;
    int i0 = 0, i1 = 0, i2 = 0;
    for (int h = 0; h < np; ++h) {
#pragma unroll
      for (int r = 0; r < 4; ++r) {
        int idx = (int)s.di[lvl][q][h][r];
        const float* c = kp + ((size_t)b * M + idx) * 3;
        double x = (double)c[0], y = (double)c[1], z = (double)c[2];
        double kn2 = (x * x + y * y) + z * z;         // ref grouping
        double dot = (qdx * x + qdy * y) + qdz * z;   // products exact
        double d2 = (qn + kn2) - 2.0 * dot;
        lexins(e0, e1, e2, i0, i1, i2, d2, idx);
      }
    }
    double d0 = fmax(e0, 0.0), d1 = fmax(e1, 0.0), d2v = fmax(e2, 0.0);
    double r0 = 1.0 / (d0 + 1e-8);
    double r1 = 1.0 / (d1 + 1e-8);
    double r2 = 1.0 / (d2v + 1e-8);
    double sum = (r0 + r1) + r2;
    float wa = (float)(r0 / sum), wb = (float)(r1 / sum), wc = (float)(r2 / sum);

    const float* fp = (lvl == 0) ? f2 : ((lvl == 1) ? f3 : f4);
    const float* g0 = fp + ((size_t)b * M + i0) * 32;
    const float* g1 = fp + ((size_t)b * M + i1) * 32;
    const float* g2 = fp + ((size_t)b * M + i2) * 32;
    float acc = 0.f;
#pragma unroll
    for (int wd = 0; wd < 32; ++wd) {
      float v = (wa * g0[wd] + wb * g1[wd]) + wc * g2[wd];
      acc += s.wv[lvl * 32 + wd] * v;
    }
    s.part[q][lvl] = acc;
  } else if (tid < 256) {
    const int q = tid - 192;
    double sm = s.mmin[q][0];
#pragma unroll
    for (int p = 1; p < 8; ++p) sm = fmin(sm, s.mmin[q][p]);
    double dm = s.qn[q] + sm;   // monotone rounding: == min of per-cand d2
    // d2 < 0.25 == sqrt(max(d2,0)) < 0.5 (monotone, both strict)
    out[NB * NQ + gqbase + q] = (dm < 0.25) ? 1.0f : 0.0f;
  }
  __syncthreads();
  if (tid < 64) {
    float pred = (s.part[tid][0] + s.part[tid][1]) + s.part[tid][2];
    out[gqbase + tid] = pred;
  }
}

extern "C" void kernel_launch(void* const* d_in, const int* in_sizes, int n_in,
                              void* d_out, int out_size, void* d_ws, size_t ws_size,
                              hipStream_t stream) {
  const float* pts    = (const float*)d_in[0];
  const float* known2 = (const float*)d_in[1];
  const float* feats2 = (const float*)d_in[2];
  const float* known3 = (const float*)d_in[3];
  const float* feats3 = (const float*)d_in[4];
  const float* known4 = (const float*)d_in[5];
  const float* feats4 = (const float*)d_in[6];
  const float* match  = (const float*)d_in[7];
  const float* wfc    = (const float*)d_in[8];
  const float* wcls   = (const float*)d_in[9];

  char* ws = (char*)d_ws;
  CP* c0 = (CP*)(ws);
  CP* c1 = (CP*)(ws + (size_t)512 * 1024);
  CP* c2 = (CP*)(ws + (size_t)768 * 1024);
  DM* cm = (DM*)(ws + (size_t)896 * 1024);

  if (ws_size >= WS_NEEDED) {
    hipLaunchKernelGGL(prep_kernel, dim3(64, 4), dim3(256), 0, stream,
                       known2, known3, known4, match, c0, c1, c2, cm);
    hipLaunchKernelGGL(fused_kernel<true>, dim3(NQ / 64, NB), dim3(512), 0,
                       stream, pts, known2, feats2, known3, feats3, known4,
                       feats4, match, wfc, wcls, c0, c1, c2, cm, (float*)d_out);
  } else {
    hipLaunchKernelGGL(fused_kernel<false>, dim3(NQ / 64, NB), dim3(512), 0,
                       stream, pts, known2, feats2, known3, feats3, known4,
                       feats4, match, wfc, wcls, c0, c1, c2, cm, (float*)d_out);
  }
}